// Round 1
// baseline (156.790 us; speedup 1.0000x reference)
//
#include <hip/hip_runtime.h>
#include <math.h>

#define H2 256
#define MAXDEG 128
#define APAD 520   // sA row stride (halves): 1040B rows -> 2-way banks (free)
#define HPAD 264   // hbuf row stride (halves): 528B rows -> 2-way banks (free)

typedef _Float16 f16x8 __attribute__((ext_vector_type(8)));
typedef _Float16 f16x4 __attribute__((ext_vector_type(4)));
typedef float f32x4 __attribute__((ext_vector_type(4)));

// ---------------------------------------------------------------------------
// Fused prep: zero cursor; nf fp32 -> catfull[:, 0:256) fp16 (row stride 512);
// W1[512][256]->W1t[256][512] fp16; W2[256][256]->W2t[256][256] fp16.
__global__ __launch_bounds__(256) void prep(
        const float* __restrict__ nf, const float* __restrict__ W1,
        const float* __restrict__ W2, int* __restrict__ cursor,
        _Float16* __restrict__ catfull, _Float16* __restrict__ W1t,
        _Float16* __restrict__ W2t, int n) {
    int flat = blockIdx.x * 256 + threadIdx.x;
    if (flat < n) cursor[flat] = 0;
    if (flat < 512 * 256) {                    // W1t idx = nn*512 + k
        int nn = flat >> 9, k = flat & 511;
        W1t[flat] = (_Float16)W1[(size_t)k * 256 + nn];
    } else if (flat < 512 * 256 + 256 * 256) { // W2t idx2 = nn*256 + k
        int idx2 = flat - 512 * 256;
        int nn = idx2 >> 8, k = idx2 & 255;
        W2t[idx2] = (_Float16)W2[(size_t)k * 256 + nn];
    }
    int wid  = threadIdx.x >> 6;
    int lane = threadIdx.x & 63;
    int row  = blockIdx.x * 4 + wid;
    if (row < n) {
        float4 v = ((const float4*)nf)[(size_t)row * 64 + lane];
        f16x4 h;
        h.x = (_Float16)v.x; h.y = (_Float16)v.y;
        h.z = (_Float16)v.z; h.w = (_Float16)v.w;
        *(f16x4*)&catfull[(size_t)row * 512 + lane * 4] = h;
    }
}

// ---------------------------------------------------------------------------
__global__ void scatter_edges(const int* __restrict__ esrc, const int* __restrict__ edst,
                              int* __restrict__ cursor, int* __restrict__ bucket, int E) {
    int e = blockIdx.x * 256 + threadIdx.x;
    if (e >= E) return;
    int d = edst[e];
    int s = esrc[e];
    int r = atomicAdd(&cursor[d], 1);
    if (r < MAXDEG) bucket[d * MAXDEG + r] = s;
}

// ---------------------------------------------------------------------------
// Standalone gather: one wave per node, 64 lanes x f16x4 cover the 256 cols.
// pooled = deg*self - sum(neighbors); written fp16 into catfull[:, 256:512).
// No LDS, no barriers, low VGPR -> high occupancy; 10000 independent waves
// give the MLP needed to hide L2/L3 gather latency. Tail handled by one
// branch-free padded 8-group (duplicate-last-index loads, zero-selected).
__global__ __launch_bounds__(256) void gather(
        const float* __restrict__ nf, const int* __restrict__ cursor,
        const int* __restrict__ bucket, _Float16* __restrict__ catfull, int M) {
    int lane = threadIdx.x & 63, wid = threadIdx.x >> 6;
    int node = blockIdx.x * 4 + wid;
    if (node >= M) return;
    int deg = cursor[node];
    int degc = deg < MAXDEG ? deg : MAXDEG;
    const int* bk = bucket + (size_t)node * MAXDEG;
    float4 accA = make_float4(0.f, 0.f, 0.f, 0.f);
    float4 accB = make_float4(0.f, 0.f, 0.f, 0.f);
    int e = 0;
    for (; e + 8 <= degc; e += 8) {
        int4 sa = *(const int4*)&bk[e];
        int4 sb = *(const int4*)&bk[e + 4];
        f16x4 v0 = *(const f16x4*)&catfull[(size_t)sa.x * 512 + lane * 4];
        f16x4 v1 = *(const f16x4*)&catfull[(size_t)sa.y * 512 + lane * 4];
        f16x4 v2 = *(const f16x4*)&catfull[(size_t)sa.z * 512 + lane * 4];
        f16x4 v3 = *(const f16x4*)&catfull[(size_t)sa.w * 512 + lane * 4];
        f16x4 v4 = *(const f16x4*)&catfull[(size_t)sb.x * 512 + lane * 4];
        f16x4 v5 = *(const f16x4*)&catfull[(size_t)sb.y * 512 + lane * 4];
        f16x4 v6 = *(const f16x4*)&catfull[(size_t)sb.z * 512 + lane * 4];
        f16x4 v7 = *(const f16x4*)&catfull[(size_t)sb.w * 512 + lane * 4];
        accA.x += ((float)v0.x + (float)v1.x) + ((float)v2.x + (float)v3.x);
        accA.y += ((float)v0.y + (float)v1.y) + ((float)v2.y + (float)v3.y);
        accA.z += ((float)v0.z + (float)v1.z) + ((float)v2.z + (float)v3.z);
        accA.w += ((float)v0.w + (float)v1.w) + ((float)v2.w + (float)v3.w);
        accB.x += ((float)v4.x + (float)v5.x) + ((float)v6.x + (float)v7.x);
        accB.y += ((float)v4.y + (float)v5.y) + ((float)v6.y + (float)v7.y);
        accB.z += ((float)v4.z + (float)v5.z) + ((float)v6.z + (float)v7.z);
        accB.w += ((float)v4.w + (float)v5.w) + ((float)v6.w + (float)v7.w);
    }
    int rem = degc - e;
    if (rem > 0) {
        f16x4 tv[8];
#pragma unroll
        for (int i = 0; i < 8; ++i) {
            int ii = e + (i < rem ? i : rem - 1);   // in-bounds duplicate of last
            tv[i] = *(const f16x4*)&catfull[(size_t)bk[ii] * 512 + lane * 4];
        }
#pragma unroll
        for (int i = 0; i < 8; ++i) {
            if (i >= rem) {   // uniform select after all loads issued
                tv[i].x = (_Float16)0; tv[i].y = (_Float16)0;
                tv[i].z = (_Float16)0; tv[i].w = (_Float16)0;
            }
        }
        accA.x += ((float)tv[0].x + (float)tv[1].x) + ((float)tv[2].x + (float)tv[3].x);
        accA.y += ((float)tv[0].y + (float)tv[1].y) + ((float)tv[2].y + (float)tv[3].y);
        accA.z += ((float)tv[0].z + (float)tv[1].z) + ((float)tv[2].z + (float)tv[3].z);
        accA.w += ((float)tv[0].w + (float)tv[1].w) + ((float)tv[2].w + (float)tv[3].w);
        accB.x += ((float)tv[4].x + (float)tv[5].x) + ((float)tv[6].x + (float)tv[7].x);
        accB.y += ((float)tv[4].y + (float)tv[5].y) + ((float)tv[6].y + (float)tv[7].y);
        accB.z += ((float)tv[4].z + (float)tv[5].z) + ((float)tv[6].z + (float)tv[7].z);
        accB.w += ((float)tv[4].w + (float)tv[5].w) + ((float)tv[6].w + (float)tv[7].w);
    }
    float4 self = ((const float4*)nf)[(size_t)node * 64 + lane];
    float fd = (float)deg;
    f16x4 o;
    o.x = (_Float16)(fd * self.x - (accA.x + accB.x));
    o.y = (_Float16)(fd * self.y - (accA.y + accB.y));
    o.z = (_Float16)(fd * self.z - (accA.z + accB.z));
    o.w = (_Float16)(fd * self.w - (accA.w + accB.w));
    *(f16x4*)&catfull[(size_t)node * 512 + 256 + lane * 4] = o;
}

// ---------------------------------------------------------------------------
// Pure 2-stage GEMM: out = tanh((catfull @ W1t + b1) @ W2t + b2).
// 512 thr / 8 waves; M-tile 16 (grid 625); wave n-tile 32.
// Stage A rows straight from catfull (b128, 2 passes). W fragments from L2
// via depth-4 register pipeline; A via LDS with 1-step prefetch; h via LDS.
__global__ __launch_bounds__(512, 4) void gemm12(
        const _Float16* __restrict__ catfull,
        const _Float16* __restrict__ W1t, const _Float16* __restrict__ W2t,
        const float* __restrict__ b1, const float* __restrict__ b2,
        float* __restrict__ out, int M) {
    __shared__ _Float16 sA[16 * APAD];     // 16.3 KB
    __shared__ _Float16 hbuf[16 * HPAD];   //  8.3 KB

    int tid = threadIdx.x, lane = tid & 63, wid = tid >> 6;   // wid 0..7
    int m0 = blockIdx.x * 16;
    int wn = wid * 32;
    int fm = lane & 15;
    int q  = lane >> 4;
    int fk = q * 8;

    // ---- stage catfull rows -> sA: 16 rows x 64 b128 groups, 2 passes
    {
        int idx = tid;
#pragma unroll
        for (int p = 0; p < 2; ++p, idx += 512) {
            int row = idx >> 6, g = (idx & 63) * 8;
            int r = m0 + row; if (r >= M) r = M - 1;
            *(uint4*)&sA[row * APAD + g] = *(const uint4*)&catfull[(size_t)r * 512 + g];
        }
    }
    __syncthreads();

    // ---- stage 1: h[16][256] = sA @ W1t + b1 ----
    size_t brow[2];
#pragma unroll
    for (int j = 0; j < 2; ++j) brow[j] = (size_t)(wn + j * 16 + fm) * 512 + fk;

    f16x8 wp[4][2];
#pragma unroll
    for (int s = 0; s < 4; ++s)
#pragma unroll
        for (int j = 0; j < 2; ++j)
            wp[s][j] = *(const f16x8*)&W1t[brow[j] + s * 32];

    f32x4 acc[2] = {};
    f16x8 a_cur = *(const f16x8*)&sA[fm * APAD + fk];
#pragma unroll
    for (int kb = 0; kb < 512; kb += 32) {
        int slot = (kb >> 5) & 3;
        f16x8 a_nxt;
        if (kb + 32 < 512) a_nxt = *(const f16x8*)&sA[fm * APAD + kb + 32 + fk];
        f16x8 w0 = wp[slot][0], w1 = wp[slot][1];
        if (kb + 128 < 512) {
            wp[slot][0] = *(const f16x8*)&W1t[brow[0] + kb + 128];
            wp[slot][1] = *(const f16x8*)&W1t[brow[1] + kb + 128];
        }
        acc[0] = __builtin_amdgcn_mfma_f32_16x16x32_f16(a_cur, w0, acc[0], 0, 0, 0);
        acc[1] = __builtin_amdgcn_mfma_f32_16x16x32_f16(a_cur, w1, acc[1], 0, 0, 0);
        if (kb + 32 < 512) a_cur = a_nxt;
    }

    // epilogue 1: hbuf[row][ncol], row = q*4+r, ncol = wn + j*16 + fm
#pragma unroll
    for (int j = 0; j < 2; ++j) {
        int ncol = wn + j * 16 + fm;
        float bv = b1[ncol];
#pragma unroll
        for (int r = 0; r < 4; ++r)
            hbuf[(q * 4 + r) * HPAD + ncol] = (_Float16)(acc[j][r] + bv);
    }
    __syncthreads();

    // ---- stage 2: out[16][256] = tanh(h @ W2t + b2) ----
    size_t brow2[2];
#pragma unroll
    for (int j = 0; j < 2; ++j) brow2[j] = (size_t)(wn + j * 16 + fm) * 256 + fk;

#pragma unroll
    for (int s = 0; s < 4; ++s)
#pragma unroll
        for (int j = 0; j < 2; ++j)
            wp[s][j] = *(const f16x8*)&W2t[brow2[j] + s * 32];

    f32x4 acc2[2] = {};
    a_cur = *(const f16x8*)&hbuf[fm * HPAD + fk];
#pragma unroll
    for (int kb = 0; kb < 256; kb += 32) {
        int slot = (kb >> 5) & 3;
        f16x8 a_nxt;
        if (kb + 32 < 256) a_nxt = *(const f16x8*)&hbuf[fm * HPAD + kb + 32 + fk];
        f16x8 w0 = wp[slot][0], w1 = wp[slot][1];
        if (kb + 128 < 256) {
            wp[slot][0] = *(const f16x8*)&W2t[brow2[0] + kb + 128];
            wp[slot][1] = *(const f16x8*)&W2t[brow2[1] + kb + 128];
        }
        acc2[0] = __builtin_amdgcn_mfma_f32_16x16x32_f16(a_cur, w0, acc2[0], 0, 0, 0);
        acc2[1] = __builtin_amdgcn_mfma_f32_16x16x32_f16(a_cur, w1, acc2[1], 0, 0, 0);
        if (kb + 32 < 256) a_cur = a_nxt;
    }

    // epilogue 2
#pragma unroll
    for (int j = 0; j < 2; ++j) {
        int ncol = wn + j * 16 + fm;
        float bv = b2[ncol];
#pragma unroll
        for (int r = 0; r < 4; ++r) {
            int row = m0 + q * 4 + r;
            if (row < M) out[(size_t)row * 256 + ncol] = tanhf(acc2[j][r] + bv);
        }
    }
}

// ---------------------------------------------------------------------------
extern "C" void kernel_launch(void* const* d_in, const int* in_sizes, int n_in,
                              void* d_out, int out_size, void* d_ws, size_t ws_size,
                              hipStream_t stream) {
    const float* nf  = (const float*)d_in[0];   // [N, 256] fp32
    const float* W1  = (const float*)d_in[1];   // [512, 256]
    const float* b1  = (const float*)d_in[2];   // [256]
    const float* W2  = (const float*)d_in[3];   // [256, 256]
    const float* b2  = (const float*)d_in[4];   // [256]
    const int* esrc  = (const int*)d_in[5];     // [E]
    const int* edst  = (const int*)d_in[6];     // [E]
    float* out = (float*)d_out;                 // [N, 256] fp32

    int N = in_sizes[0] / H2;
    int E = in_sizes[5];

    char* ws = (char*)d_ws;
    size_t off = 0;
    auto take = [&](size_t bytes) { size_t o = off; off += (bytes + 255) / 256 * 256; return o; };
    int*       cursor  = (int*)(ws + take((size_t)N * 4));
    int*       bucket  = (int*)(ws + take((size_t)N * MAXDEG * 4));
    _Float16*  catfull = (_Float16*)(ws + take((size_t)N * 512 * 2));
    _Float16*  W1t     = (_Float16*)(ws + take(512 * 256 * 2));
    _Float16*  W2t     = (_Float16*)(ws + take(256 * 256 * 2));

    prep<<<(N + 3) / 4, 256, 0, stream>>>(nf, W1, W2, cursor, catfull, W1t, W2t, N);
    scatter_edges<<<(E + 255) / 256, 256, 0, stream>>>(esrc, edst, cursor, bucket, E);
    gather<<<(N + 3) / 4, 256, 0, stream>>>(nf, cursor, bucket, catfull, N);
    gemm12<<<(N + 15) / 16, 512, 0, stream>>>(catfull, W1t, W2t, b1, b2, out, N);
}